// Round 15
// baseline (778.940 us; speedup 1.0000x reference)
//
#include <hip/hip_runtime.h>

typedef __attribute__((ext_vector_type(8))) short short8;
typedef __attribute__((ext_vector_type(4))) short short4v;
typedef __attribute__((ext_vector_type(4))) float f32x4;

#define MFMA16(a,b,c) __builtin_amdgcn_mfma_f32_16x16x32_bf16((a),(b),(c),0,0,0)

// Pre-transposed bf16 mixing weights: w0T | w1rT w1iT -w1iT | ... | w4iT -w4iT
__device__ __align__(16) short g_wt[117760];
// Fragment-order mixing weights: [unit][k][lane64][8 shorts] (coalesced wave loads)
__device__ __align__(16) short g_wtf[148480];
// Pre-transposed bf16 radial weights fcwT[160][64]
__device__ __align__(16) short g_fcwt[10240];

// ---------------- compile-time mixing schedule (no dummy steps) ----------------
struct K2Tab {
  int   fbase[50];
  int   pboff[50][8];
  short acoeff[50][8];
  short len[50];
  short dm[50];
  short ut[50];
  short ocoeff[50];
  short lsc[50];
  short co16[50];
  short pu[290];
  short pk[290];
};

constexpr K2Tab make_k2tab() {
  K2Tab T{};
  const int P[5][5]  = {{0,2,6,12,20},{3,7,13,21,0},{8,14,22,0,0},{15,23,0,0,0},{24,0,0,0,0}};
  const int Ng[5][5] = {{0,0,0,0,0},{1,5,11,19,0},{4,10,18,0,0},{9,17,0,0,0},{16,0,0,0,0}};
  const int WR[5]  = {0, 25600, 74752, 102400, 114688};
  const int WI[5]  = {0, 41984, 83968, 106496, 115712};
  const int NWI[5] = {0, 58368, 93184, 110592, 116736};
  const int ms[9]  = {1,1,2,2,0,3,3,4,4};
  const int hs[9]  = {0,1,0,1,0,0,1,0,1};
  const int ntc[9] = {8,8,6,6,10,4,4,2,2};
  int u = 0, fb = 0, np = 0;
  for (int g = 0; g < 9; ++g) {
    const int m = ms[g], h = hs[g];
    const int dm = (m == 0) ? 160 : (5 - m) * 32;
    const int lm = (m == 0) ? 5 : (5 - m);
    const int len = (m == 0) ? 5 : 2 * lm;
    const int b1 = (m == 0) ? 0 : ((h == 0) ? WR[m] : WI[m]);
    const int b2 = (m == 0) ? 0 : ((h == 0) ? NWI[m] : WR[m]);
    for (int tt = 0; tt < ntc[g]; ++tt, ++u) {
      T.dm[u] = (short)dm; T.len[u] = (short)len; T.ut[u] = (short)tt;
      const int lo = tt >> 1;
      T.ocoeff[u] = (short)((m == 0) ? P[0][lo] : ((h == 0) ? P[m][lo] : Ng[m][lo]));
      T.lsc[u] = (short)(m + lo);
      T.co16[u] = (short)((tt & 1) * 16);
      T.fbase[u] = fb;
      for (int k = 0; k < len; ++k) {
        int bb, ac;
        if (m == 0)      { bb = k * 32;            ac = P[0][k]; }
        else if (k < lm) { bb = b1 + k * 32;       ac = P[m][k]; }
        else             { bb = b2 + (k - lm) * 32; ac = Ng[m][k - lm]; }
        T.pboff[u][k] = bb; T.acoeff[u][k] = (short)ac;
        T.pu[np] = (short)u; T.pk[np] = (short)k; ++np;
      }
      fb += len * 512;
    }
  }
  return T;   // np == 290, fb == 148480
}
__constant__ K2Tab c_kt = make_k2tab();

__device__ __forceinline__ short f2bf(float f) {
  unsigned u = __float_as_uint(f);
  u += 0x7FFFu + ((u >> 16) & 1u);
  return (short)(u >> 16);
}
__device__ __forceinline__ unsigned f2bf_pk(float lo, float hi) {
  unsigned a = __float_as_uint(lo);
  a += 0x7FFFu + ((a >> 16) & 1u);
  unsigned b = __float_as_uint(hi);
  b += 0x7FFFu + ((b >> 16) & 1u);
  return (a >> 16) | (b & 0xFFFF0000u);
}

__global__ void prep_weights(const float* __restrict__ w0,
    const float* __restrict__ w1r, const float* __restrict__ w1i,
    const float* __restrict__ w2r, const float* __restrict__ w2i,
    const float* __restrict__ w3r, const float* __restrict__ w3i,
    const float* __restrict__ w4r, const float* __restrict__ w4i,
    const float* __restrict__ fcw) {
  int idx = blockIdx.x * 256 + threadIdx.x;
  if (idx >= 128000) return;
  if (idx >= 117760) {
    int local = idx - 117760;
    int n = local >> 6, k = local & 63;
    g_fcwt[local] = f2bf(fcw[k * 160 + n]);
    return;
  }
  int off, dm; const float* src; bool neg = false;
  if (idx < 25600)       { off = 0;      dm = 160; src = w0;  }
  else if (idx < 41984)  { off = 25600;  dm = 128; src = w1r; }
  else if (idx < 58368)  { off = 41984;  dm = 128; src = w1i; }
  else if (idx < 74752)  { off = 58368;  dm = 128; src = w1i; neg = true; }
  else if (idx < 83968)  { off = 74752;  dm = 96;  src = w2r; }
  else if (idx < 93184)  { off = 83968;  dm = 96;  src = w2i; }
  else if (idx < 102400) { off = 93184;  dm = 96;  src = w2i; neg = true; }
  else if (idx < 106496) { off = 102400; dm = 64;  src = w3r; }
  else if (idx < 110592) { off = 106496; dm = 64;  src = w3i; }
  else if (idx < 114688) { off = 110592; dm = 64;  src = w3i; neg = true; }
  else if (idx < 115712) { off = 114688; dm = 32;  src = w4r; }
  else if (idx < 116736) { off = 115712; dm = 32;  src = w4i; }
  else                   { off = 116736; dm = 32;  src = w4i; neg = true; }
  int local = idx - off;
  int n = local / dm, k = local - n * dm;
  float v = src[k * dm + n];
  g_wt[idx] = f2bf(neg ? -v : v);
}

// repack g_wt -> fragment-order g_wtf
__global__ void prep_frags() {
  int i = blockIdx.x * 256 + threadIdx.x;
  if (i >= 290 * 512) return;
  int p = i >> 9;
  int w = i & 511;
  int lane = w >> 3, j = w & 7;
  int l15 = lane & 15, lg = lane >> 4;
  int u = c_kt.pu[p], k = c_kt.pk[p];
  int col = (int)c_kt.ut[u] * 16 + l15;
  g_wtf[i] = g_wt[c_kt.pboff[u][k] + col * (int)c_kt.dm[u] + lg * 8 + j];
}

// ---------------- counting sort of edges by dst ----------------
__global__ void hist_kernel(const int* __restrict__ edst, int* __restrict__ cnt, int E) {
  int i = blockIdx.x * 256 + threadIdx.x;
  if (i < E) atomicAdd(&cnt[edst[i]], 1);
}

__global__ __launch_bounds__(1024) void scan_kernel(
    const int* __restrict__ cnt, int* __restrict__ cursor, int N) {
  __shared__ int s[1024];
  const int t = threadIdx.x;
  int v[10]; int sum = 0;
  #pragma unroll
  for (int k = 0; k < 10; ++k) {
    int i = t * 10 + k;
    v[k] = (i < N) ? cnt[i] : 0;
    sum += v[k];
  }
  s[t] = sum;
  __syncthreads();
  for (int d = 1; d < 1024; d <<= 1) {
    int add = (t >= d) ? s[t - d] : 0;
    __syncthreads();
    s[t] += add;
    __syncthreads();
  }
  int prefix = s[t] - sum;
  #pragma unroll
  for (int k = 0; k < 10; ++k) {
    int i = t * 10 + k;
    if (i < N) cursor[i] = prefix;
    prefix += v[k];
  }
}

__global__ void scatter_kernel(const int* __restrict__ edst, int* __restrict__ cursor,
                               int* __restrict__ order, int E) {
  int i = blockIdx.x * 256 + threadIdx.x;
  if (i < E) {
    int p = atomicAdd(&cursor[edst[i]], 1);
    order[p] = i;
  }
}

// ================= K12: fused gather + fwd-rotation + mixing, 32 edges/block =================
#define ESTRIDE 1048
#define SMEM_K12 78080   // 32*1048*2 + 32*168*2 + 256

__global__ __launch_bounds__(512, 4) void k12_fused(
    const float* __restrict__ x, const float* __restrict__ wig,
    const float* __restrict__ efc, const int* __restrict__ esrc,
    const int* __restrict__ order, const float* __restrict__ fcb,
    short* __restrict__ y, int E)
{
  extern __shared__ char smem[];
  short*     s_buf  = (short*)smem;                    // 32 * 1048 shorts
  _Float16*  s_sc   = (_Float16*)(smem + 67072);       // 32 * 168
  int*       s_meta = (int*)(smem + 77824);            // [0..31] og, [32..63] src

  const int tid = threadIdx.x;
  const int lane = tid & 63;
  const int wid = tid >> 6;        // 0..7
  const int l15 = lane & 15;
  const int lg  = lane >> 4;
  const int koff = lg * 8;
  const int e0  = blockIdx.x * 32;

  // zero K-pad coeff rows 25-31
  for (int o = tid; o < 3584; o += 512) {
    int e = o / 112, q = o - e * 112;
    ((int*)s_buf)[e * 524 + 400 + q] = 0;
  }
  if (tid < 32) {
    int idx = min(e0 + tid, E - 1);
    int og = order[idx];
    s_meta[tid] = og;
    s_meta[32 + tid] = esrc[og];
  }
  __syncthreads();

  // ---- stage xe un-transposed ----
  for (int o = tid; o < 25600; o += 512) {
    int e = o / 800, q = o - e * 800;
    s_buf[e * ESTRIDE + q] = f2bf(x[(size_t)s_meta[32 + e] * 800 + q]);
  }
  // ---- silu scales via MFMA ----
  {
    const int mt = wid >> 2;
    const int ge = s_meta[mt * 16 + l15];
    const float* ep = efc + (size_t)ge * 64;
    float4 fa = *(const float4*)(ep + lg * 8);
    float4 fb = *(const float4*)(ep + lg * 8 + 4);
    float4 fc = *(const float4*)(ep + 32 + lg * 8);
    float4 fd = *(const float4*)(ep + 32 + lg * 8 + 4);
    short8 af0, af1;
    af0[0]=f2bf(fa.x); af0[1]=f2bf(fa.y); af0[2]=f2bf(fa.z); af0[3]=f2bf(fa.w);
    af0[4]=f2bf(fb.x); af0[5]=f2bf(fb.y); af0[6]=f2bf(fb.z); af0[7]=f2bf(fb.w);
    af1[0]=f2bf(fc.x); af1[1]=f2bf(fc.y); af1[2]=f2bf(fc.z); af1[3]=f2bf(fc.w);
    af1[4]=f2bf(fd.x); af1[5]=f2bf(fd.y); af1[6]=f2bf(fd.z); af1[7]=f2bf(fd.w);
    for (int nt = (wid & 3); nt < 10; nt += 4) {
      const int f = nt * 16 + l15;
      const short* bp = g_fcwt + f * 64 + lg * 8;
      short8 b0 = *(const short8*)(bp);
      short8 b1 = *(const short8*)(bp + 32);
      f32x4 acc = {0.f, 0.f, 0.f, 0.f};
      acc = MFMA16(af0, b0, acc);
      acc = MFMA16(af1, b1, acc);
      float bias = fcb[f];
      #pragma unroll
      for (int r = 0; r < 4; ++r) {
        float vv = acc[r] + bias;
        s_sc[(mt * 16 + lg * 4 + r) * 168 + (f >> 5) * 33 + (f & 31)] =
            (_Float16)(vv / (1.f + __expf(-vv)));
      }
    }
  }
  __syncthreads();

  // ---- forward rotation IN-PLACE: each wave owns edges wid*4 .. wid*4+3 ----
  #pragma unroll 4
  for (int i = 0; i < 4; ++i) {
    const int e = wid * 4 + i;
    short* eb = s_buf + e * ESTRIDE;
    const float* wp = wig + (size_t)s_meta[e] * 625;
    short8 a0, a1;
    #pragma unroll
    for (int j = 0; j < 8; ++j) {
      const int k = koff + j;
      a0[j] = eb[k * 32 + l15];
      a1[j] = eb[k * 32 + 16 + l15];
    }
    short8 b0, b1;
    const int r1 = min(16 + l15, 24);
    #pragma unroll
    for (int j = 0; j < 8; ++j) {
      const int k = koff + j;
      const int kc = min(k, 24);
      const short v0 = f2bf(wp[l15 * 25 + kc]);
      const short v1 = f2bf(wp[r1 * 25 + kc]);
      b0[j] = (k < 25) ? v0 : (short)0;
      b1[j] = (k < 25) ? v1 : (short)0;
    }
    f32x4 d00 = {0.f,0.f,0.f,0.f}, d01 = {0.f,0.f,0.f,0.f};
    f32x4 d10 = {0.f,0.f,0.f,0.f}, d11 = {0.f,0.f,0.f,0.f};
    d00 = MFMA16(a0, b0, d00);
    d01 = MFMA16(a0, b1, d01);
    d10 = MFMA16(a1, b0, d10);
    d11 = MFMA16(a1, b1, d11);
    short4v v;
    v[0]=f2bf(d00[0]); v[1]=f2bf(d00[1]); v[2]=f2bf(d00[2]); v[3]=f2bf(d00[3]);
    *(short4v*)(eb + l15 * 32 + lg * 4) = v;
    v[0]=f2bf(d10[0]); v[1]=f2bf(d10[1]); v[2]=f2bf(d10[2]); v[3]=f2bf(d10[3]);
    *(short4v*)(eb + l15 * 32 + 16 + lg * 4) = v;
    if (l15 < 9) {
      v[0]=f2bf(d01[0]); v[1]=f2bf(d01[1]); v[2]=f2bf(d01[2]); v[3]=f2bf(d01[3]);
      *(short4v*)(eb + (16 + l15) * 32 + lg * 4) = v;
      v[0]=f2bf(d11[0]); v[1]=f2bf(d11[1]); v[2]=f2bf(d11[2]); v[3]=f2bf(d11[3]);
      *(short4v*)(eb + (16 + l15) * 32 + 16 + lg * 4) = v;
    }
  }
  __syncthreads();

  // ---- SO(2) mixing: 50 units / 8 waves, B reused across 2 M-tiles ----
  // Epilogue: in-wave 4x4 transpose (2x shfl_xor) -> one 8B store per lane
  const int bq = l15 & 3;     // col-within-quad, becomes row selector after transpose
  const int aq = l15 >> 2;    // col-quad
  for (int u = wid; u < 50; u += 8) {
    const int len = c_kt.len[u];
    const short* Bp = g_wtf + c_kt.fbase[u] + lane * 8;
    short8 B[8];
    #pragma unroll 8
    for (int k = 0; k < 8; ++k)
      if (k < len) B[k] = *(const short8*)(Bp + (k << 9));
    const int co = c_kt.co16[u] + l15;
    const int oc = c_kt.ocoeff[u];
    const int ls = c_kt.lsc[u];
    #pragma unroll 2
    for (int mt = 0; mt < 2; ++mt) {
      const short* xl = s_buf + (mt * 16 + l15) * ESTRIDE + koff;
      f32x4 acc0 = {0.f,0.f,0.f,0.f}, acc1 = {0.f,0.f,0.f,0.f};
      #pragma unroll 8
      for (int k = 0; k < 8; ++k) {
        if (k < len) {
          short8 a = *(const short8*)(xl + (int)c_kt.acoeff[u][k] * 32);
          if (k & 1) acc1 = MFMA16(a, B[k], acc1);
          else       acc0 = MFMA16(a, B[k], acc0);
        }
      }
      f32x4 acc = acc0 + acc1;
      // scale rows (per edge el, own col co)
      float v0 = acc[0] * (float)s_sc[(mt*16 + lg*4 + 0) * 168 + ls * 33 + co];
      float v1 = acc[1] * (float)s_sc[(mt*16 + lg*4 + 1) * 168 + ls * 33 + co];
      float v2 = acc[2] * (float)s_sc[(mt*16 + lg*4 + 2) * 168 + ls * 33 + co];
      float v3 = acc[3] * (float)s_sc[(mt*16 + lg*4 + 3) * 168 + ls * 33 + co];
      unsigned u0 = f2bf_pk(v0, v1);   // rows(0,1) of my col
      unsigned u1 = f2bf_pk(v2, v3);   // rows(2,3) of my col
      // xor2: u0 = rows(R) low col, u1 = rows(R) high col, R = {0,1} or {2,3} by bq&2
      unsigned t = __shfl_xor((bq & 2) ? u0 : u1, 2, 64);
      if (bq & 2) u0 = t; else u1 = t;
      // xor1: merge 16-bit halves -> lane bq holds row bq, 4 contiguous cols
      unsigned t0 = __shfl_xor(u0, 1, 64);
      unsigned t1 = __shfl_xor(u1, 1, 64);
      unsigned w0, w1;
      if (bq & 1) {
        w0 = (t0 >> 16) | (u0 & 0xFFFF0000u);
        w1 = (t1 >> 16) | (u1 & 0xFFFF0000u);
      } else {
        w0 = (u0 & 0xFFFFu) | (t0 << 16);
        w1 = (u1 & 0xFFFFu) | (t1 << 16);
      }
      const int el = mt * 16 + lg * 4 + bq;
      const int slot = e0 + el;
      if (slot < E) {
        int2 w; w.x = (int)w0; w.y = (int)w1;
        *(int2*)(y + (size_t)slot * 800 + oc * 32 + c_kt.co16[u] + aq * 4) = w;
      }
    }
  }
}

// ================= K3: back-rotation + segmented sorted flush =================
__global__ __launch_bounds__(256, 5) void k3_back(
    const short* __restrict__ y, const float* __restrict__ wig,
    const int* __restrict__ edst, const int* __restrict__ order,
    const int* __restrict__ cnt, float* __restrict__ out, int E)
{
  __shared__ __align__(16) char sumem[27136];
  __shared__ int s_meta[64];
  short* s_y  = (short*)sumem;
  float* yb_s = (float*)sumem;

  const int tid = threadIdx.x;
  const int lane = tid & 63;
  const int wid = tid >> 6;
  const int l15 = lane & 15;
  const int lg  = lane >> 4;
  const int e0  = blockIdx.x * 8;

  for (int o = tid; o < 5216; o += 256) ((int*)sumem)[o] = 0;
  if (tid < 8) {
    int idx = e0 + tid;
    bool v = idx < E;
    int og = order[v ? idx : 0];
    s_meta[tid] = og;
    s_meta[16 + tid] = v ? edst[og] : -1;
  }
  __syncthreads();

  if (wid == 0) {
    int dj = (lane < 8) ? s_meta[16 + lane] : -1;
    bool valid = (lane < 8) && (dj >= 0);
    bool is_start = valid && (lane == 0 || dj != s_meta[16 + lane - 1]);
    unsigned long long vm = __ballot(valid);
    unsigned long long sm = __ballot(is_start);
    int nv = __popcll(vm);
    int ng = __popcll(sm);
    if (lane == 0) s_meta[24] = ng;
    if ((int)lane < ng) {
      int s = -1, c = -1;
      for (int b = 0; b < 8; ++b) { if ((sm >> b) & 1) { ++c; if (c == (int)lane) { s = b; break; } } }
      int e_ = nv;
      for (int b = s + 1; b < 8; ++b) if ((sm >> b) & 1) { e_ = b; break; }
      int d = s_meta[16 + s];
      s_meta[25 + lane] = d;
      s_meta[33 + lane] = s;
      s_meta[41 + lane] = e_;
      s_meta[49 + lane] = ((e_ - s) == cnt[d]) ? 1 : 0;
    }
  }
  for (int o = tid; o < 800; o += 256) {
    int e = o / 100, r = o - e * 100;
    int slot = min(e0 + e, E - 1);
    int q = r * 8;
    *(short8*)(s_y + e * 1304 + (q >> 5) * 40 + (q & 31)) =
        *(const short8*)(y + (size_t)slot * 800 + q);
  }
  __syncthreads();

  f32x4 r00[2], r01[2], r10[2], r11[2];
  #pragma unroll
  for (int i = 0; i < 2; ++i) {
    const int e = wid * 2 + i;
    const short* yb = s_y + e * 1304 + lg * 8 * 40;
    const float* wp = wig + (size_t)s_meta[e] * 625;
    short8 a0, a1, b0, b1;
    const int c2 = min(16 + l15, 24);
    #pragma unroll 8
    for (int j = 0; j < 8; ++j) {
      a0[j] = yb[j * 40 + l15];
      a1[j] = yb[j * 40 + 16 + l15];
      const int k = lg * 8 + j;
      const int kc = min(k, 24);
      const short v0 = f2bf(wp[kc * 25 + l15]);
      const short v1 = f2bf(wp[kc * 25 + c2]);
      b0[j] = (k < 25) ? v0 : (short)0;
      b1[j] = (k < 25) ? v1 : (short)0;
    }
    f32x4 d00 = {0.f,0.f,0.f,0.f}, d01 = {0.f,0.f,0.f,0.f};
    f32x4 d10 = {0.f,0.f,0.f,0.f}, d11 = {0.f,0.f,0.f,0.f};
    d00 = MFMA16(a0, b0, d00);
    d01 = MFMA16(a0, b1, d01);
    d10 = MFMA16(a1, b0, d10);
    d11 = MFMA16(a1, b1, d11);
    r00[i] = d00; r01[i] = d01; r10[i] = d10; r11[i] = d11;
  }
  __syncthreads();

  #pragma unroll
  for (int i = 0; i < 2; ++i) {
    const int e = wid * 2 + i;
    float* yb = yb_s + e * 840;
    #pragma unroll 4
    for (int r = 0; r < 4; ++r) {
      yb[l15 * 33 + lg * 4 + r]      = r00[i][r];
      yb[l15 * 33 + 16 + lg * 4 + r] = r10[i][r];
    }
    if (l15 < 9) {
      #pragma unroll 4
      for (int r = 0; r < 4; ++r) {
        yb[(16 + l15) * 33 + lg * 4 + r]      = r01[i][r];
        yb[(16 + l15) * 33 + 16 + lg * 4 + r] = r11[i][r];
      }
    }
  }
  __syncthreads();

  const int ng = s_meta[24];
  for (int o = tid; o < 800; o += 256) {
    const int yoff = (o >> 5) * 33 + (o & 31);
    for (int g = 0; g < ng; ++g) {
      float sum = 0.f;
      const int gs = s_meta[33 + g], ge = s_meta[41 + g];
      for (int e = gs; e < ge; ++e) sum += yb_s[e * 840 + yoff];
      float* ad = out + (size_t)s_meta[25 + g] * 800 + o;
      if (s_meta[49 + g]) *ad = sum;
      else atomicAdd(ad, sum);
    }
  }
}

extern "C" void kernel_launch(void* const* d_in, const int* in_sizes, int n_in,
                              void* d_out, int out_size, void* d_ws, size_t ws_size,
                              hipStream_t stream) {
  const float* x    = (const float*)d_in[0];
  const float* wigp = (const float*)d_in[1];
  const float* efc  = (const float*)d_in[2];
  const int*   esrc = (const int*)d_in[3];
  const int*   edst = (const int*)d_in[4];
  const float* w0   = (const float*)d_in[5];
  const float* w1r  = (const float*)d_in[6];
  const float* w1i  = (const float*)d_in[7];
  const float* w2r  = (const float*)d_in[8];
  const float* w2i  = (const float*)d_in[9];
  const float* w3r  = (const float*)d_in[10];
  const float* w3i  = (const float*)d_in[11];
  const float* w4r  = (const float*)d_in[12];
  const float* w4i  = (const float*)d_in[13];
  const float* fcw  = (const float*)d_in[14];
  const float* fcb  = (const float*)d_in[15];
  float* out = (float*)d_out;
  const int E = in_sizes[3];
  const int N = out_size / 800;

  int* cnt    = (int*)d_ws;
  int* cursor = cnt + N;
  int* order  = cnt + 2 * N;
  size_t y_off = (((size_t)(2 * N + E) * 4) + 255) & ~(size_t)255;
  short* yb = (short*)((char*)d_ws + y_off);   // E*800 bf16 = 256 MB

  hipFuncSetAttribute((const void*)k12_fused,
                      hipFuncAttributeMaxDynamicSharedMemorySize, SMEM_K12);

  prep_weights<<<(128000 + 255) / 256, 256, 0, stream>>>(
      w0, w1r, w1i, w2r, w2i, w3r, w3i, w4r, w4i, fcw);
  prep_frags<<<(290 * 512 + 255) / 256, 256, 0, stream>>>();

  hipMemsetAsync(d_out, 0, (size_t)out_size * sizeof(float), stream);
  hipMemsetAsync(cnt, 0, (size_t)N * sizeof(int), stream);

  hist_kernel<<<(E + 255) / 256, 256, 0, stream>>>(edst, cnt, E);
  scan_kernel<<<1, 1024, 0, stream>>>(cnt, cursor, N);
  scatter_kernel<<<(E + 255) / 256, 256, 0, stream>>>(edst, cursor, order, E);

  k12_fused<<<(E + 31) / 32, 512, SMEM_K12, stream>>>(
      x, wigp, efc, esrc, order, fcb, yb, E);
  k3_back<<<(E + 7) / 8, 256, 0, stream>>>(yb, wigp, edst, order, cnt, out, E);
}

// Round 16
// 704.150 us; speedup vs baseline: 1.1062x; 1.1062x over previous
//
#include <hip/hip_runtime.h>

typedef __attribute__((ext_vector_type(8))) short short8;
typedef __attribute__((ext_vector_type(4))) short short4v;
typedef __attribute__((ext_vector_type(4))) float f32x4;

#define MFMA16(a,b,c) __builtin_amdgcn_mfma_f32_16x16x32_bf16((a),(b),(c),0,0,0)

// Pre-transposed bf16 mixing weights: w0T | w1rT w1iT -w1iT | ... | w4iT -w4iT
__device__ __align__(16) short g_wt[117760];
// Fragment-order mixing weights: [unit][k][lane64][8 shorts]
__device__ __align__(16) short g_wtf[148480];
// Pre-transposed bf16 radial weights fcwT[160][64]
__device__ __align__(16) short g_fcwt[10240];

// ---------------- compile-time mixing schedule ----------------
struct K2Tab {
  int   fbase[50];
  int   pboff[50][8];
  short acoeff[50][8];
  short len[50];
  short dm[50];
  short ut[50];
  short ocoeff[50];
  short lsc[50];
  short co16[50];
  short pu[290];
  short pk[290];
};

constexpr K2Tab make_k2tab() {
  K2Tab T{};
  const int P[5][5]  = {{0,2,6,12,20},{3,7,13,21,0},{8,14,22,0,0},{15,23,0,0,0},{24,0,0,0,0}};
  const int Ng[5][5] = {{0,0,0,0,0},{1,5,11,19,0},{4,10,18,0,0},{9,17,0,0,0},{16,0,0,0,0}};
  const int WR[5]  = {0, 25600, 74752, 102400, 114688};
  const int WI[5]  = {0, 41984, 83968, 106496, 115712};
  const int NWI[5] = {0, 58368, 93184, 110592, 116736};
  const int ms[9]  = {1,1,2,2,0,3,3,4,4};
  const int hs[9]  = {0,1,0,1,0,0,1,0,1};
  const int ntc[9] = {8,8,6,6,10,4,4,2,2};
  int u = 0, fb = 0, np = 0;
  for (int g = 0; g < 9; ++g) {
    const int m = ms[g], h = hs[g];
    const int dm = (m == 0) ? 160 : (5 - m) * 32;
    const int lm = (m == 0) ? 5 : (5 - m);
    const int len = (m == 0) ? 5 : 2 * lm;
    const int b1 = (m == 0) ? 0 : ((h == 0) ? WR[m] : WI[m]);
    const int b2 = (m == 0) ? 0 : ((h == 0) ? NWI[m] : WR[m]);
    for (int tt = 0; tt < ntc[g]; ++tt, ++u) {
      T.dm[u] = (short)dm; T.len[u] = (short)len; T.ut[u] = (short)tt;
      const int lo = tt >> 1;
      T.ocoeff[u] = (short)((m == 0) ? P[0][lo] : ((h == 0) ? P[m][lo] : Ng[m][lo]));
      T.lsc[u] = (short)(m + lo);
      T.co16[u] = (short)((tt & 1) * 16);
      T.fbase[u] = fb;
      for (int k = 0; k < len; ++k) {
        int bb, ac;
        if (m == 0)      { bb = k * 32;            ac = P[0][k]; }
        else if (k < lm) { bb = b1 + k * 32;       ac = P[m][k]; }
        else             { bb = b2 + (k - lm) * 32; ac = Ng[m][k - lm]; }
        T.pboff[u][k] = bb; T.acoeff[u][k] = (short)ac;
        T.pu[np] = (short)u; T.pk[np] = (short)k; ++np;
      }
      fb += len * 512;
    }
  }
  return T;   // np == 290, fb == 148480
}
__constant__ K2Tab c_kt = make_k2tab();

__device__ __forceinline__ short f2bf(float f) {
  unsigned u = __float_as_uint(f);
  u += 0x7FFFu + ((u >> 16) & 1u);
  return (short)(u >> 16);
}

__global__ void prep_weights(const float* __restrict__ w0,
    const float* __restrict__ w1r, const float* __restrict__ w1i,
    const float* __restrict__ w2r, const float* __restrict__ w2i,
    const float* __restrict__ w3r, const float* __restrict__ w3i,
    const float* __restrict__ w4r, const float* __restrict__ w4i,
    const float* __restrict__ fcw) {
  int idx = blockIdx.x * 256 + threadIdx.x;
  if (idx >= 128000) return;
  if (idx >= 117760) {
    int local = idx - 117760;
    int n = local >> 6, k = local & 63;
    g_fcwt[local] = f2bf(fcw[k * 160 + n]);
    return;
  }
  int off, dm; const float* src; bool neg = false;
  if (idx < 25600)       { off = 0;      dm = 160; src = w0;  }
  else if (idx < 41984)  { off = 25600;  dm = 128; src = w1r; }
  else if (idx < 58368)  { off = 41984;  dm = 128; src = w1i; }
  else if (idx < 74752)  { off = 58368;  dm = 128; src = w1i; neg = true; }
  else if (idx < 83968)  { off = 74752;  dm = 96;  src = w2r; }
  else if (idx < 93184)  { off = 83968;  dm = 96;  src = w2i; }
  else if (idx < 102400) { off = 93184;  dm = 96;  src = w2i; neg = true; }
  else if (idx < 106496) { off = 102400; dm = 64;  src = w3r; }
  else if (idx < 110592) { off = 106496; dm = 64;  src = w3i; }
  else if (idx < 114688) { off = 110592; dm = 64;  src = w3i; neg = true; }
  else if (idx < 115712) { off = 114688; dm = 32;  src = w4r; }
  else if (idx < 116736) { off = 115712; dm = 32;  src = w4i; }
  else                   { off = 116736; dm = 32;  src = w4i; neg = true; }
  int local = idx - off;
  int n = local / dm, k = local - n * dm;
  float v = src[k * dm + n];
  g_wt[idx] = f2bf(neg ? -v : v);
}

__global__ void prep_frags() {
  int i = blockIdx.x * 256 + threadIdx.x;
  if (i >= 290 * 512) return;
  int p = i >> 9;
  int w = i & 511;
  int lane = w >> 3, j = w & 7;
  int l15 = lane & 15, lg = lane >> 4;
  int u = c_kt.pu[p], k = c_kt.pk[p];
  int col = (int)c_kt.ut[u] * 16 + l15;
  g_wtf[i] = g_wt[c_kt.pboff[u][k] + col * (int)c_kt.dm[u] + lg * 8 + j];
}

// ---------------- counting sort of edges by dst ----------------
__global__ void hist_kernel(const int* __restrict__ edst, int* __restrict__ cnt, int E) {
  int i = blockIdx.x * 256 + threadIdx.x;
  if (i < E) atomicAdd(&cnt[edst[i]], 1);
}

__global__ __launch_bounds__(1024) void scan_kernel(
    const int* __restrict__ cnt, int* __restrict__ cursor, int N) {
  __shared__ int s[1024];
  const int t = threadIdx.x;
  int v[10]; int sum = 0;
  #pragma unroll
  for (int k = 0; k < 10; ++k) {
    int i = t * 10 + k;
    v[k] = (i < N) ? cnt[i] : 0;
    sum += v[k];
  }
  s[t] = sum;
  __syncthreads();
  for (int d = 1; d < 1024; d <<= 1) {
    int add = (t >= d) ? s[t - d] : 0;
    __syncthreads();
    s[t] += add;
    __syncthreads();
  }
  int prefix = s[t] - sum;
  #pragma unroll
  for (int k = 0; k < 10; ++k) {
    int i = t * 10 + k;
    if (i < N) cursor[i] = prefix;
    prefix += v[k];
  }
}

__global__ void scatter_kernel(const int* __restrict__ edst, int* __restrict__ cursor,
                               int* __restrict__ order, int E) {
  int i = blockIdx.x * 256 + threadIdx.x;
  if (i < E) {
    int p = atomicAdd(&cursor[edst[i]], 1);
    order[p] = i;
  }
}

// ================= K_ALL: fully fused per 16 sorted edges =================
// LDS: s_buf [16][1048]s (xe->xr) | s_y [16][1024]s | s_sc [16][168]h | s_meta int[116]
// yb f32 [16][840] overlays s_buf+s_y after back-rotation.
#define ESTRIDE 1048
#define YSTRIDE 1024
#define SMEM_ALL 72144

__global__ __launch_bounds__(512, 4) void k_all(
    const float* __restrict__ x, const float* __restrict__ wig,
    const float* __restrict__ efc, const int* __restrict__ esrc,
    const int* __restrict__ edst, const int* __restrict__ order,
    const float* __restrict__ fcb, const int* __restrict__ cnt,
    float* __restrict__ out, int E)
{
  extern __shared__ char smem[];
  short*    s_buf  = (short*)smem;                  // 33536 B
  short*    s_y    = (short*)(smem + 33536);        // 32768 B
  _Float16* s_sc   = (_Float16*)(smem + 66304);     // 5376 B
  int*      s_meta = (int*)(smem + 71680);          // 464 B
  float*    yb_s   = (float*)smem;                  // overlay [16][840]

  const int tid = threadIdx.x;
  const int lane = tid & 63;
  const int wid = tid >> 6;        // 0..7
  const int l15 = lane & 15;
  const int lg  = lane >> 4;
  const int koff = lg * 8;
  const int e0  = blockIdx.x * 16;

  // zero K-pad rows 25-31 of s_buf and s_y
  for (int o = tid; o < 1792; o += 512) {
    int e = o / 112, q = o - e * 112;
    ((int*)s_buf)[e * 524 + 400 + q] = 0;
  }
  for (int o = tid; o < 1792; o += 512) {
    int e = o / 112, q = o - e * 112;
    ((int*)s_y)[e * 512 + 400 + q] = 0;
  }
  if (tid < 16) {
    int idx = e0 + tid;
    bool v = idx < E;
    int og = order[v ? idx : 0];
    s_meta[tid] = og;
    s_meta[16 + tid] = esrc[og];
    s_meta[32 + tid] = v ? edst[og] : -1;
  }
  __syncthreads();

  // ---- group build (wave 0, lanes 0-15) ----
  if (wid == 0) {
    int dj = (lane < 16) ? s_meta[32 + lane] : -1;
    bool valid = (lane < 16) && (dj >= 0);
    bool is_start = valid && (lane == 0 || dj != s_meta[32 + lane - 1]);
    unsigned long long vm = __ballot(valid);
    unsigned long long sm = __ballot(is_start);
    int nv = __popcll(vm);
    int ng = __popcll(sm);
    if (lane == 0) s_meta[48] = ng;
    if ((int)lane < ng) {
      int s = -1, c = -1;
      for (int b = 0; b < 16; ++b) { if ((sm >> b) & 1) { ++c; if (c == (int)lane) { s = b; break; } } }
      int e_ = nv;
      for (int b = s + 1; b < 16; ++b) if ((sm >> b) & 1) { e_ = b; break; }
      int d = s_meta[32 + s];
      s_meta[49 + lane] = d;
      s_meta[65 + lane] = s;
      s_meta[81 + lane] = e_;
      s_meta[97 + lane] = ((e_ - s) == cnt[d]) ? 1 : 0;
    }
  }

  // ---- stage xe (un-transposed) ----
  for (int o = tid; o < 12800; o += 512) {
    int e = o / 800, q = o - e * 800;
    s_buf[e * ESTRIDE + q] = f2bf(x[(size_t)s_meta[16 + e] * 800 + q]);
  }
  // ---- silu scales via MFMA ----
  {
    const int ge = s_meta[l15];
    const float* ep = efc + (size_t)ge * 64;
    float4 fa = *(const float4*)(ep + lg * 8);
    float4 fb = *(const float4*)(ep + lg * 8 + 4);
    float4 fc = *(const float4*)(ep + 32 + lg * 8);
    float4 fd = *(const float4*)(ep + 32 + lg * 8 + 4);
    short8 af0, af1;
    af0[0]=f2bf(fa.x); af0[1]=f2bf(fa.y); af0[2]=f2bf(fa.z); af0[3]=f2bf(fa.w);
    af0[4]=f2bf(fb.x); af0[5]=f2bf(fb.y); af0[6]=f2bf(fb.z); af0[7]=f2bf(fb.w);
    af1[0]=f2bf(fc.x); af1[1]=f2bf(fc.y); af1[2]=f2bf(fc.z); af1[3]=f2bf(fc.w);
    af1[4]=f2bf(fd.x); af1[5]=f2bf(fd.y); af1[6]=f2bf(fd.z); af1[7]=f2bf(fd.w);
    for (int nt = wid; nt < 10; nt += 8) {
      const int f = nt * 16 + l15;
      const short* bp = g_fcwt + f * 64 + lg * 8;
      short8 b0 = *(const short8*)(bp);
      short8 b1 = *(const short8*)(bp + 32);
      f32x4 acc = {0.f, 0.f, 0.f, 0.f};
      acc = MFMA16(af0, b0, acc);
      acc = MFMA16(af1, b1, acc);
      float bias = fcb[f];
      #pragma unroll
      for (int r = 0; r < 4; ++r) {
        float vv = acc[r] + bias;
        s_sc[(lg * 4 + r) * 168 + (f >> 5) * 33 + (f & 31)] =
            (_Float16)(vv / (1.f + __expf(-vv)));
      }
    }
  }
  __syncthreads();

  // ---- forward rotation IN-PLACE: each wave owns edges wid*2, wid*2+1 ----
  #pragma unroll 2
  for (int i = 0; i < 2; ++i) {
    const int e = wid * 2 + i;
    short* eb = s_buf + e * ESTRIDE;
    const float* wp = wig + (size_t)s_meta[e] * 625;
    short8 a0, a1;
    #pragma unroll
    for (int j = 0; j < 8; ++j) {
      const int k = koff + j;
      a0[j] = eb[k * 32 + l15];
      a1[j] = eb[k * 32 + 16 + l15];
    }
    short8 b0, b1;
    const int r1 = min(16 + l15, 24);
    #pragma unroll
    for (int j = 0; j < 8; ++j) {
      const int k = koff + j;
      const int kc = min(k, 24);
      const short v0 = f2bf(wp[l15 * 25 + kc]);
      const short v1 = f2bf(wp[r1 * 25 + kc]);
      b0[j] = (k < 25) ? v0 : (short)0;
      b1[j] = (k < 25) ? v1 : (short)0;
    }
    f32x4 d00 = {0.f,0.f,0.f,0.f}, d01 = {0.f,0.f,0.f,0.f};
    f32x4 d10 = {0.f,0.f,0.f,0.f}, d11 = {0.f,0.f,0.f,0.f};
    d00 = MFMA16(a0, b0, d00);
    d01 = MFMA16(a0, b1, d01);
    d10 = MFMA16(a1, b0, d10);
    d11 = MFMA16(a1, b1, d11);
    short4v v;
    v[0]=f2bf(d00[0]); v[1]=f2bf(d00[1]); v[2]=f2bf(d00[2]); v[3]=f2bf(d00[3]);
    *(short4v*)(eb + l15 * 32 + lg * 4) = v;
    v[0]=f2bf(d10[0]); v[1]=f2bf(d10[1]); v[2]=f2bf(d10[2]); v[3]=f2bf(d10[3]);
    *(short4v*)(eb + l15 * 32 + 16 + lg * 4) = v;
    if (l15 < 9) {
      v[0]=f2bf(d01[0]); v[1]=f2bf(d01[1]); v[2]=f2bf(d01[2]); v[3]=f2bf(d01[3]);
      *(short4v*)(eb + (16 + l15) * 32 + lg * 4) = v;
      v[0]=f2bf(d11[0]); v[1]=f2bf(d11[1]); v[2]=f2bf(d11[2]); v[3]=f2bf(d11[3]);
      *(short4v*)(eb + (16 + l15) * 32 + 16 + lg * 4) = v;
    }
  }
  __syncthreads();

  // ---- SO(2) mixing: 50 units / 8 waves, y -> s_y (LDS) ----
  for (int u = wid; u < 50; u += 8) {
    const int len = c_kt.len[u];
    const short* Bp = g_wtf + c_kt.fbase[u] + lane * 8;
    short8 B[8];
    #pragma unroll 8
    for (int k = 0; k < 8; ++k)
      if (k < len) B[k] = *(const short8*)(Bp + (k << 9));
    const int co = c_kt.co16[u] + l15;
    const int oc = c_kt.ocoeff[u];
    const int ls = c_kt.lsc[u];
    const short* xl = s_buf + l15 * ESTRIDE + koff;
    f32x4 acc0 = {0.f,0.f,0.f,0.f}, acc1 = {0.f,0.f,0.f,0.f};
    #pragma unroll 8
    for (int k = 0; k < 8; ++k) {
      if (k < len) {
        short8 a = *(const short8*)(xl + (int)c_kt.acoeff[u][k] * 32);
        if (k & 1) acc1 = MFMA16(a, B[k], acc1);
        else       acc0 = MFMA16(a, B[k], acc0);
      }
    }
    f32x4 acc = acc0 + acc1;
    #pragma unroll
    for (int r = 0; r < 4; ++r) {
      const int el = lg * 4 + r;
      float sc = (float)s_sc[el * 168 + ls * 33 + co];
      s_y[el * YSTRIDE + oc * 32 + co] = f2bf(acc[r] * sc);
    }
  }
  __syncthreads();

  // ---- back-rotation: yb = W^T @ y, 2 edges/wave; wigner 2nd read (L2-hot) ----
  f32x4 r00[2], r01[2], r10[2], r11[2];
  #pragma unroll 2
  for (int i = 0; i < 2; ++i) {
    const int e = wid * 2 + i;
    const short* yb = s_y + e * YSTRIDE;
    const float* wp = wig + (size_t)s_meta[e] * 625;
    short8 a0, a1, b0, b1;
    const int c2 = min(16 + l15, 24);
    #pragma unroll 8
    for (int j = 0; j < 8; ++j) {
      const int k = koff + j;
      a0[j] = yb[k * 32 + l15];
      a1[j] = yb[k * 32 + 16 + l15];
      const int kc = min(k, 24);
      const short v0 = f2bf(wp[kc * 25 + l15]);
      const short v1 = f2bf(wp[kc * 25 + c2]);
      b0[j] = (k < 25) ? v0 : (short)0;
      b1[j] = (k < 25) ? v1 : (short)0;
    }
    f32x4 d00 = {0.f,0.f,0.f,0.f}, d01 = {0.f,0.f,0.f,0.f};
    f32x4 d10 = {0.f,0.f,0.f,0.f}, d11 = {0.f,0.f,0.f,0.f};
    d00 = MFMA16(a0, b0, d00);
    d01 = MFMA16(a0, b1, d01);
    d10 = MFMA16(a1, b0, d10);
    d11 = MFMA16(a1, b1, d11);
    r00[i] = d00; r01[i] = d01; r10[i] = d10; r11[i] = d11;
  }
  __syncthreads();   // all s_y/s_buf reads complete before yb overlay

  // ---- yb f32 overlay ----
  #pragma unroll 2
  for (int i = 0; i < 2; ++i) {
    const int e = wid * 2 + i;
    float* yb = yb_s + e * 840;
    #pragma unroll 4
    for (int r = 0; r < 4; ++r) {
      yb[l15 * 33 + lg * 4 + r]      = r00[i][r];
      yb[l15 * 33 + 16 + lg * 4 + r] = r10[i][r];
    }
    if (l15 < 9) {
      #pragma unroll 4
      for (int r = 0; r < 4; ++r) {
        yb[(16 + l15) * 33 + lg * 4 + r]      = r01[i][r];
        yb[(16 + l15) * 33 + 16 + lg * 4 + r] = r11[i][r];
      }
    }
  }
  __syncthreads();

  // ---- segmented flush ----
  const int ng = s_meta[48];
  for (int o = tid; o < 800; o += 512) {
    const int yoff = (o >> 5) * 33 + (o & 31);
    for (int g = 0; g < ng; ++g) {
      float sum = 0.f;
      const int gs = s_meta[65 + g], ge = s_meta[81 + g];
      for (int e = gs; e < ge; ++e) sum += yb_s[e * 840 + yoff];
      float* ad = out + (size_t)s_meta[49 + g] * 800 + o;
      if (s_meta[97 + g]) *ad = sum;
      else atomicAdd(ad, sum);
    }
  }
}

extern "C" void kernel_launch(void* const* d_in, const int* in_sizes, int n_in,
                              void* d_out, int out_size, void* d_ws, size_t ws_size,
                              hipStream_t stream) {
  const float* x    = (const float*)d_in[0];
  const float* wigp = (const float*)d_in[1];
  const float* efc  = (const float*)d_in[2];
  const int*   esrc = (const int*)d_in[3];
  const int*   edst = (const int*)d_in[4];
  const float* w0   = (const float*)d_in[5];
  const float* w1r  = (const float*)d_in[6];
  const float* w1i  = (const float*)d_in[7];
  const float* w2r  = (const float*)d_in[8];
  const float* w2i  = (const float*)d_in[9];
  const float* w3r  = (const float*)d_in[10];
  const float* w3i  = (const float*)d_in[11];
  const float* w4r  = (const float*)d_in[12];
  const float* w4i  = (const float*)d_in[13];
  const float* fcw  = (const float*)d_in[14];
  const float* fcb  = (const float*)d_in[15];
  float* out = (float*)d_out;
  const int E = in_sizes[3];
  const int N = out_size / 800;

  int* cnt    = (int*)d_ws;
  int* cursor = cnt + N;
  int* order  = cnt + 2 * N;

  hipFuncSetAttribute((const void*)k_all,
                      hipFuncAttributeMaxDynamicSharedMemorySize, SMEM_ALL);

  prep_weights<<<(128000 + 255) / 256, 256, 0, stream>>>(
      w0, w1r, w1i, w2r, w2i, w3r, w3i, w4r, w4i, fcw);
  prep_frags<<<(290 * 512 + 255) / 256, 256, 0, stream>>>();

  hipMemsetAsync(d_out, 0, (size_t)out_size * sizeof(float), stream);
  hipMemsetAsync(cnt, 0, (size_t)N * sizeof(int), stream);

  hist_kernel<<<(E + 255) / 256, 256, 0, stream>>>(edst, cnt, E);
  scan_kernel<<<1, 1024, 0, stream>>>(cnt, cursor, N);
  scatter_kernel<<<(E + 255) / 256, 256, 0, stream>>>(edst, cursor, order, E);

  k_all<<<(E + 15) / 16, 512, SMEM_ALL, stream>>>(
      x, wigp, efc, esrc, edst, order, fcb, cnt, out, E);
}